// Round 14
// baseline (37.137 us; speedup 1.0000x reference)
//
#include <hip/hip_runtime.h>
#include <math.h>

#define BATCH 8
#define NBOX 10000
#define NCLS 80
#define KSEL 8
#define MAXT 8
#define IOU_THR 0.5f
#define SCORE_THR 0.5f
#define NEGV -1000000000.0f
#define IDXINF 0x7fffffff

#define NSUB 80             // 128-row subs per class (K1): 80*128 = 10240
#define CHROWS 640          // fallback chunk = 5 subs = 640 rows; 16 chunks
typedef unsigned long long u64;

// Packed key, order-isomorphic to (val desc, idx asc); val>SCORE_THR>0 so
// float bits are monotone. bits: [51:20] value, [19:6] 16383-idx, [5:0] lane.
__device__ __forceinline__ u64 pk20(float v, int n) {
    return ((u64)__float_as_uint(v) << 20) | ((u64)(16383 - n) << 6);
}

// threshold + top-2 update (ascending n -> first-idx ties)
#define T2C(V1, I1, V2, I2, X, N)                                           \
    do {                                                                    \
        float _x = ((X) > SCORE_THR) ? (X) : NEGV;                          \
        if (_x > (V1)) { (V2)=(V1); (I2)=(I1); (V1)=_x; (I1)=(N); }         \
        else if (_x > (V2)) { (V2)=_x; (I2)=(N); }                          \
    } while (0)

// sorted-4 insertion (descending); zero keys never displace real ones
#define INS4(T1, T2, T3, T4, K)                                             \
    do { u64 _k = (K);                                                      \
        if (_k > (T1)) { (T4)=(T3); (T3)=(T2); (T2)=(T1); (T1)=_k; }        \
        else if (_k > (T2)) { (T4)=(T3); (T3)=(T2); (T2)=_k; }              \
        else if (_k > (T3)) { (T4)=(T3); (T3)=_k; }                         \
        else if (_k > (T4)) { (T4)=_k; }                                    \
    } while (0)

// IoU suppression, per-op IEEE rounding identical to numpy reference;
// union = kept_area + cand_area (fadd_rn is commutative -> bit-identical).
#define IOU_SUP(KB, KA)                                                     \
    do {                                                                    \
        float ih = fmaxf(__fsub_rn(fminf((KB).z, cb.z), fmaxf((KB).x, cb.x)), 0.0f); \
        float iw = fmaxf(__fsub_rn(fminf((KB).w, cb.w), fmaxf((KB).y, cb.y)), 0.0f); \
        float inter = __fmul_rn(ih, iw);                                    \
        float uni   = __fsub_rn(__fadd_rn((KA), carea), inter);             \
        float iou   = __fdiv_rn(inter, fmaxf(uni, 1e-9f));                  \
        if (iou > IOU_THR) sup = true;                                      \
    } while (0)

__device__ __forceinline__ float aload(const float* p) {
    return __hip_atomic_load(p, __ATOMIC_RELAXED, __HIP_MEMORY_SCOPE_AGENT);
}

// ---------------------------------------------------------------------------
// K1: per-(batch, 128-row sub) top-2 packed keys for all 80 classes (pairs).
// Reads raw (B,N,C) once, coalesced float4 across classes. (validated R10)
// ---------------------------------------------------------------------------
__global__ __launch_bounds__(320) void class_heads(
    const float* __restrict__ scores,   // (B, N, C)
    u64* __restrict__ hk,               // (B*C, NSUB, 2) packed keys
    int* __restrict__ cnt)              // (BATCH) completion counters
{
    __shared__ u64 lk[16][NCLS][2];     // 20 KB

    const int bid = blockIdx.x;         // b + 8*sub -> XCD pin
    const int b   = bid & 7;
    const int sub = bid >> 3;
    const int n0  = sub * 128;
    const int tid = threadIdx.x;
    const int q   = tid % 20;           // class quad
    const int g   = tid / 20;           // row group [0,16)

    if (bid == 0 && tid < BATCH) cnt[tid] = 0;

    const float* base = scores + ((size_t)b * NBOX + n0) * NCLS + 4 * q;

    float v10 = NEGV, v20 = NEGV, v11 = NEGV, v21 = NEGV;
    float v12 = NEGV, v22 = NEGV, v13 = NEGV, v23 = NEGV;
    int   i10 = IDXINF, i20 = IDXINF, i11 = IDXINF, i21 = IDXINF;
    int   i12 = IDXINF, i22 = IDXINF, i13 = IDXINF, i23 = IDXINF;

    #pragma unroll
    for (int k = 0; k < 8; ++k) {
        const int n = n0 + g * 8 + k;
        if (n < NBOX) {
            float4 x = *(const float4*)(base + (size_t)(g * 8 + k) * NCLS);
            T2C(v10, i10, v20, i20, x.x, n);
            T2C(v11, i11, v21, i21, x.y, n);
            T2C(v12, i12, v22, i22, x.z, n);
            T2C(v13, i13, v23, i23, x.w, n);
        }
    }

    const int c0 = 4 * q;
    lk[g][c0 + 0][0] = (v10 > SCORE_THR) ? pk20(v10, i10) : 0;
    lk[g][c0 + 0][1] = (v20 > SCORE_THR) ? pk20(v20, i20) : 0;
    lk[g][c0 + 1][0] = (v11 > SCORE_THR) ? pk20(v11, i11) : 0;
    lk[g][c0 + 1][1] = (v21 > SCORE_THR) ? pk20(v21, i21) : 0;
    lk[g][c0 + 2][0] = (v12 > SCORE_THR) ? pk20(v12, i12) : 0;
    lk[g][c0 + 2][1] = (v22 > SCORE_THR) ? pk20(v22, i22) : 0;
    lk[g][c0 + 3][0] = (v13 > SCORE_THR) ? pk20(v13, i13) : 0;
    lk[g][c0 + 3][1] = (v23 > SCORE_THR) ? pk20(v23, i23) : 0;
    __syncthreads();

    if (tid < NCLS) {
        u64 h1 = 0, h2 = 0;
        #pragma unroll
        for (int g2 = 0; g2 < 16; ++g2) {
            u64 a1 = lk[g2][tid][0], a2 = lk[g2][tid][1];   // a1 >= a2
            if (a1 > h1) { u64 t = h1; h1 = a1; h2 = (a2 > t) ? a2 : t; }
            else if (a1 > h2) h2 = a1;
        }
        u64* o = hk + ((size_t)(b * NCLS + tid) * NSUB + sub) * 2;
        o[0] = h1; o[1] = h2;
    }
}

// ---------------------------------------------------------------------------
// K1.5: per-class chunk top-8 rank-select at HIGH occupancy (10 waves/CU),
// PLUS the head-box gather — scattered loads hidden by TLP here, so K2 can
// load boxes coalesced. Empty slots zero-filled (replay-safe).
// ---------------------------------------------------------------------------
__global__ __launch_bounds__(256) void chunk_heads(
    const u64* __restrict__ hk,         // (B*C, NSUB*2) linear keys
    const float* __restrict__ boxes,    // (B,N,4)
    u64* __restrict__ sk8,              // (B*C, 64) sorted chunk top-8 keys
    float4* __restrict__ sbx)           // (B*C, 64) matching boxes
{
    __shared__ u64 keys[8][20];         // 1.3 KB

    const int bc  = blockIdx.x;
    const int b   = bc / NCLS;
    const int tid = threadIdx.x;
    if (tid < 160) keys[tid / 20][tid % 20] = hk[(size_t)bc * 160 + tid];
    __syncthreads();

    const int ch  = tid >> 5;           // chunk [0,8)
    const int l32 = tid & 31;
    const float4* box4 = (const float4*)(boxes + (size_t)b * NBOX * 4);

    const u64 mykey = (l32 < 20) ? keys[ch][l32] : 0;
    int rank = 0, nnz = 0;
    #pragma unroll
    for (int i = 0; i < 20; ++i) {      // independent compares (ILP)
        const u64 ki = keys[ch][i];
        rank += (ki > mykey) ? 1 : 0;
        nnz  += (ki != 0) ? 1 : 0;
    }
    u64*    o  = sk8 + (size_t)bc * 64 + ch * 8;
    float4* ob = sbx + (size_t)bc * 64 + ch * 8;
    if (mykey != 0 && rank < 8) {
        o[rank]  = mykey;               // unique keys -> no dup
        ob[rank] = box4[16383 - (int)((mykey >> 6) & 0x3FFF)];
    }
    const int fill = (nnz < 8) ? nnz : 8;
    if (l32 >= fill && l32 < 8) {
        o[l32]  = 0;
        ob[l32] = make_float4(0.f, 0.f, 0.f, 0.f);
    }
}

// ---------------------------------------------------------------------------
// K2: one WAVE per class. Coalesced head+box load; one-shot rank; lanes
// redistributed by rank; per-lane 64-IoU suppressor bitmask (pure VALU
// throughput); greedy closure = <=8 iterations of {ffs + shift + ballot}
// (no memory in the chain). Exactness check else validated 16x4 fallback.
// Last block per batch runs the fused top-8 combine.
// ---------------------------------------------------------------------------
__global__ __launch_bounds__(256) void nms_extract(
    const u64* __restrict__ hk,
    const u64* __restrict__ sk8,
    const float4* __restrict__ sbx,
    const float* __restrict__ scores,   // raw (B,N,C)
    const float* __restrict__ boxes,    // (B,N,4)
    float* __restrict__ ws_msc,
    float* __restrict__ ws_box,         // (B*C*K, 4) floats
    int*   __restrict__ cnt,
    float* __restrict__ out)
{
    __shared__ u64    kds[4][64];       // lane-indexed keys
    __shared__ float4 bds[4][64];       // lane-indexed boxes
    __shared__ int    lut[4][64];       // rank -> lane
    __shared__ u64    kr[4][64];        // rank-indexed keys
    __shared__ float4 br[4][64];        // rank-indexed boxes
    __shared__ float  rv[2][4];
    __shared__ int    ri[2][4];
    __shared__ int    s_old;

    const int bid = blockIdx.x;         // b + 8*grp -> XCD pin
    const int b   = bid & 7;
    const int grp = bid >> 3;
    const int w   = threadIdx.x >> 6;
    const int l   = threadIdx.x & 63;
    const int tid = threadIdx.x;
    const int c   = grp * 4 + w;
    const int bc  = b * NCLS + c;

    const float*  raw  = scores + (size_t)b * NBOX * NCLS + c;
    const float4* box4 = (const float4*)(boxes + (size_t)b * NBOX * 4);

    const int r8 = l & 7;               // rank within chunk (l>>3 = chunk)

    // ---- coalesced loads (both streams adjacent in ws) ----
    const u64    k  = sk8[(size_t)bc * 64 + l];
    const float4 bx = sbx[(size_t)bc * 64 + l];

    // ---- one-shot rank (uniform b128 broadcast reads) ----
    kds[w][l] = k;
    bds[w][l] = bx;
    int rank = 0;
    {
        const ulonglong2* kp = (const ulonglong2*)kds[w];
        #pragma unroll
        for (int j = 0; j < 32; ++j) {
            ulonglong2 t = kp[j];
            rank += (t.x > k) ? 1 : 0;
            rank += (t.y > k) ? 1 : 0;
        }
    }
    if (k) lut[w][rank] = l;
    const int live = __popcll(__ballot(k != 0));

    // ---- redistribute by rank: lane r holds rank-r candidate ----
    u64    rk = 0;
    float4 rb = make_float4(0.f, 0.f, 0.f, 0.f);
    if (l < live) {
        const int src = lut[w][l];
        rk = kds[w][src];
        rb = bds[w][src];
    }
    kr[w][l] = rk;
    br[w][l] = rb;
    const float ra = __fmul_rn(__fsub_rn(rb.z, rb.x), __fsub_rn(rb.w, rb.y));

    // ---- per-lane suppressor bitmask: bit j = rank-j box suppresses me ----
    u64 mymask = 0;
    {
        const float4* bp = br[w];
        #pragma unroll
        for (int j = 0; j < 64; ++j) {
            const float4 kb = bp[j];    // uniform LDS read (throughput)
            const float kba = __fmul_rn(__fsub_rn(kb.z, kb.x),
                                        __fsub_rn(kb.w, kb.y));
            float ih = fmaxf(__fsub_rn(fminf(kb.z, rb.z), fmaxf(kb.x, rb.x)), 0.0f);
            float iw = fmaxf(__fsub_rn(fminf(kb.w, rb.w), fmaxf(kb.y, rb.y)), 0.0f);
            float inter = __fmul_rn(ih, iw);
            float uni   = __fsub_rn(__fadd_rn(kba, ra), inter);
            float iou   = __fdiv_rn(inter, fmaxf(uni, 1e-9f));
            if (j < l && iou > IOU_THR) mymask |= 1ull << j;
        }
    }

    // ---- greedy closure: <=8 x {ffs + shift + ballot}, register-only ----
    u64 alive = (live >= 64) ? ~0ull : ((1ull << live) - 1ull);
    u64 kept8 = 0;
    int cnt8  = 0;
    int lastr = 0;
    while (alive) {
        const int r = __ffsll((long long)alive) - 1;   // lowest live rank
        kept8 |= 1ull << r;
        lastr = r;
        alive &= ~(1ull << r);
        if (++cnt8 == MAXT) break;
        alive &= ~__ballot((mymask >> r) & 1);
    }
    const u64 term = (cnt8 == MAXT) ? kr[w][lastr] : 0;   // uniform LDS read

    // ---- exactness: any chunk's 8th head above the termination key? ----
    const u64 bad = __ballot((r8 == 7) && (k != 0) && (k > term));

    if (!bad) {
        if ((kept8 >> l) & 1) {
            const int slot = (int)__popcll(kept8 & ((1ull << l) - 1ull));
            const int o = bc * KSEL + slot;
            ws_msc[o] = __uint_as_float((unsigned)(rk >> 20));
            float* ob = ws_box + (size_t)o * 4;
            ob[0] = rb.x; ob[1] = rb.y; ob[2] = rb.z; ob[3] = rb.w;
        }
        if (l >= cnt8 && l < MAXT) {
            const int o = bc * KSEL + l;
            ws_msc[o] = NEGV;
            float* ob = ws_box + (size_t)o * 4;
            ob[0] = 0.f; ob[1] = 0.f; ob[2] = 0.f; ob[3] = 0.f;
        }
    } else {
        // ---------- FALLBACK: validated 16x4 round loop (exact) ----------
        const int ch = l >> 2;          // 16 chunks x 5 subs (640 rows)
        const int r4 = l & 3;
        u64 k4 = 0;
        {
            u64 t1 = 0, t2 = 0, t3 = 0, t4 = 0;
            const u64* hp = hk + ((size_t)bc * NSUB + ch * 5) * 2;
            #pragma unroll
            for (int j = 0; j < 10; ++j) INS4(t1, t2, t3, t4, hp[j]);
            k4 = (r4 == 0) ? t1 : (r4 == 1) ? t2 : (r4 == 2) ? t3 : t4;
        }
        float4 fbx = make_float4(0.f, 0.f, 0.f, 0.f);
        float  fba = 0.f;
        if (k4) {
            const int n = 16383 - (int)((k4 >> 6) & 0x3FFF);
            fbx = box4[n];
            fba = __fmul_rn(__fsub_rn(fbx.z, fbx.x), __fsub_rn(fbx.w, fbx.y));
        }
        u64  fkey = k4 ? (k4 | (u64)l) : 0;
        bool dead = (fkey == 0);
        const u64 zb = __ballot(k4 == 0);
        bool exh  = (zb >> (l | 3)) & 1;
        u64  fl   = 0;

        float4 kb0, kb1, kb2, kb3, kb4, kb5, kb6, kb7;
        float  ka0=0, ka1=0, ka2=0, ka3=0, ka4=0, ka5=0, ka6=0, ka7=0;
        kb0 = kb1 = kb2 = kb3 = kb4 = kb5 = kb6 = kb7 = make_float4(0, 0, 0, 0);
        int kept = 0;

        for (;;) {
            u64 lk_ = dead ? 0ull : fkey;
            #pragma unroll
            for (int off = 1; off < 64; off <<= 1) {
                u64 o = __shfl_xor(lk_, off, 64);
                if (o > lk_) lk_ = o;
            }
            const u64 db = __ballot(dead);
            const bool blind = (((db >> (l & ~3)) & 15ull) == 15ull)
                             && (fl != 0) && !exh;
            if (__any(blind)) {
                u64 fk = blind ? fl : 0ull;
                #pragma unroll
                for (int off = 1; off < 64; off <<= 1) {
                    u64 o = __shfl_xor(fk, off, 64);
                    if (o > fk) fk = o;
                }
                if (fk > lk_) {
                    const int chr = ((int)(fk & 63ull)) >> 2;
                    const u64 flc = fk & ~63ull;
                    const int nb  = chr * CHROWS;
                    u64 s1 = 0, s2 = 0, s3 = 0, s4 = 0;
                    #pragma unroll
                    for (int qq = 0; qq < 10; ++qq) {
                        const int n = nb + qq * 64 + l;
                        if (n < NBOX) {
                            float x = raw[(size_t)n * NCLS];
                            if (x > SCORE_THR) {
                                u64 kx = pk20(x, n);
                                if (kx < flc) INS4(s1, s2, s3, s4, kx);
                            }
                        }
                    }
                    #pragma unroll
                    for (int off = 1; off < 64; off <<= 1) {
                        u64 o1 = __shfl_xor(s1, off, 64);
                        u64 o2 = __shfl_xor(s2, off, 64);
                        u64 o3 = __shfl_xor(s3, off, 64);
                        u64 o4 = __shfl_xor(s4, off, 64);
                        INS4(s1, s2, s3, s4, o1); INS4(s1, s2, s3, s4, o2);
                        INS4(s1, s2, s3, s4, o3); INS4(s1, s2, s3, s4, o4);
                    }
                    if (ch == chr) {
                        u64 t = (r4 == 0) ? s1 : (r4 == 1) ? s2
                              : (r4 == 2) ? s3 : s4;
                        exh  = (s4 == 0);
                        fkey = t ? (t | (u64)l) : 0;
                        dead = (fkey == 0);
                        fl   = 0;
                        if (!dead) {
                            const int n = 16383 - (int)((fkey >> 6) & 0x3FFF);
                            fbx = box4[n];
                            fba = __fmul_rn(__fsub_rn(fbx.z, fbx.x),
                                            __fsub_rn(fbx.w, fbx.y));
                        }
                    }
                    continue;
                }
            }
            if (lk_ == 0ull) break;

            const int   owner = (int)(lk_ & 63ull);
            const float bv    = __uint_as_float((unsigned)(lk_ >> 20));
            float4 cb;
            cb.x = __shfl(fbx.x, owner, 64);
            cb.y = __shfl(fbx.y, owner, 64);
            cb.z = __shfl(fbx.z, owner, 64);
            cb.w = __shfl(fbx.w, owner, 64);
            const float carea = __shfl(fba, owner, 64);

            bool sup2 = false;
            {
                bool sup = false;
                if (kept > 0) IOU_SUP(kb0, ka0);
                if (kept > 1) IOU_SUP(kb1, ka1);
                if (kept > 2) IOU_SUP(kb2, ka2);
                if (kept > 3) IOU_SUP(kb3, ka3);
                if (kept > 4) IOU_SUP(kb4, ka4);
                if (kept > 5) IOU_SUP(kb5, ka5);
                if (kept > 6) IOU_SUP(kb6, ka6);
                if (kept > 7) IOU_SUP(kb7, ka7);
                sup2 = sup;
            }

            if (!sup2) {
                if (l == 0) {
                    const int o = bc * KSEL + kept;
                    ws_msc[o] = bv;
                    float* ob = ws_box + (size_t)o * 4;
                    ob[0] = cb.x; ob[1] = cb.y; ob[2] = cb.z; ob[3] = cb.w;
                }
                if      (kept == 0) { kb0 = cb; ka0 = carea; }
                else if (kept == 1) { kb1 = cb; ka1 = carea; }
                else if (kept == 2) { kb2 = cb; ka2 = carea; }
                else if (kept == 3) { kb3 = cb; ka3 = carea; }
                else if (kept == 4) { kb4 = cb; ka4 = carea; }
                else if (kept == 5) { kb5 = cb; ka5 = carea; }
                else if (kept == 6) { kb6 = cb; ka6 = carea; }
                else                { kb7 = cb; ka7 = carea; }
                kept++;
            }

            if (l == owner) dead = true;
            if (ch == (owner >> 2) && !exh) fl = lk_;
            if (kept == MAXT) break;
        }

        if (l == 0) {
            for (int k2 = kept; k2 < MAXT; ++k2) {
                const int o = bc * KSEL + k2;
                ws_msc[o] = NEGV;
                float* ob = ws_box + (size_t)o * 4;
                ob[0] = 0.f; ob[1] = 0.f; ob[2] = 0.f; ob[3] = 0.f;
            }
        }
    }

    // ---- last-block election for this batch -> fused top-8 combine ----
    __syncthreads();
    if (tid == 0) {
        __threadfence();
        s_old = atomicAdd(&cnt[b], 1);
    }
    __syncthreads();
    if (s_old != (NCLS / 4) - 1) return;
    __threadfence();

    const float* msc = ws_msc + b * NCLS * KSEL;
    float v0 = aload(msc + tid);
    float v1 = aload(msc + tid + 256);
    float v2 = (tid + 512 < NCLS * KSEL) ? aload(msc + tid + 512) : -INFINITY;

    const int OFF_SC = BATCH * MAXT * 4;
    const int OFF_CL = OFF_SC + BATCH * MAXT;
    const int OFF_VD = OFF_CL + BATCH * MAXT;

    int tot = 0;
    int p = 0;
    #pragma unroll
    for (int t = 0; t < MAXT; ++t) {
        float bv = v0; int bi = tid;
        if (v1 > bv) { bv = v1; bi = tid + 256; }   // ascending i -> first max
        if (v2 > bv) { bv = v2; bi = tid + 512; }
        #pragma unroll
        for (int off = 32; off > 0; off >>= 1) {
            float ov = __shfl_down(bv, off, 64);
            int   oi = __shfl_down(bi, off, 64);
            if (ov > bv || (ov == bv && oi < bi)) { bv = ov; bi = oi; }
        }
        if ((tid & 63) == 0) { rv[p][tid >> 6] = bv; ri[p][tid >> 6] = bi; }
        __syncthreads();
        bv = rv[p][0]; bi = ri[p][0];
        #pragma unroll
        for (int w2 = 1; w2 < 4; ++w2) {
            float ov = rv[p][w2]; int oi = ri[p][w2];
            if (ov > bv || (ov == bv && oi < bi)) { bv = ov; bi = oi; }
        }
        p ^= 1;

        const bool valid = bv > SCORE_THR;
        tot += valid ? 1 : 0;
        if (tid == t) {
            const float* sb = ws_box + ((size_t)b * NCLS * KSEL + bi) * 4;
            float bx0 = aload(sb + 0), bx1 = aload(sb + 1);
            float bx2 = aload(sb + 2), bx3 = aload(sb + 3);
            float* ob = out + ((size_t)b * MAXT + t) * 4;
            ob[0] = valid ? fminf(fmaxf(bx0, 0.0f), 1.0f) : 0.0f;
            ob[1] = valid ? fminf(fmaxf(bx1, 0.0f), 1.0f) : 0.0f;
            ob[2] = valid ? fminf(fmaxf(bx2, 0.0f), 1.0f) : 0.0f;
            ob[3] = valid ? fminf(fmaxf(bx3, 0.0f), 1.0f) : 0.0f;
            out[OFF_SC + b * MAXT + t] = valid ? bv : 0.0f;
            out[OFF_CL + b * MAXT + t] = valid ? (float)(bi >> 3) : 0.0f;
        }
        if (tid == (bi & 255)) {
            int w2 = bi >> 8;
            if (w2 == 0) v0 = -INFINITY;
            else if (w2 == 1) v1 = -INFINITY;
            else v2 = -INFINITY;
        }
    }
    if (tid == 0) out[OFF_VD + b] = (float)tot;
}

extern "C" void kernel_launch(void* const* d_in, const int* in_sizes, int n_in,
                              void* d_out, int out_size, void* d_ws, size_t ws_size,
                              hipStream_t stream) {
    const float* boxes  = (const float*)d_in[0];   // (B, N, 1, 4)
    const float* scores = (const float*)d_in[1];   // (B, N, C)
    float* out = (float*)d_out;

    // ws: hk (800K) | sk8 (320K) | sbx (640K) | msc (20K) | box (80K) | cnt
    const size_t nk = (size_t)BATCH * NCLS * NSUB * 2;       // 102400 keys
    char* p = (char*)d_ws;
    u64*    hk     = (u64*)p;         p += nk * 8;
    u64*    sk8    = (u64*)p;         p += (size_t)BATCH * NCLS * 64 * 8;
    float4* sbx    = (float4*)p;      p += (size_t)BATCH * NCLS * 64 * 16;
    float*  ws_msc = (float*)p;       p += (size_t)BATCH * NCLS * KSEL * 4;
    float*  ws_box = (float*)p;       p += (size_t)BATCH * NCLS * KSEL * 16;
    int*    cnt    = (int*)p;

    class_heads<<<BATCH * NSUB, 320, 0, stream>>>(scores, hk, cnt);
    chunk_heads<<<BATCH * NCLS, 256, 0, stream>>>(hk, boxes, sk8, sbx);
    nms_extract<<<BATCH * (NCLS / 4), 256, 0, stream>>>(hk, sk8, sbx, scores,
                                                        boxes, ws_msc, ws_box,
                                                        cnt, out);
}

// Round 15
// 29.236 us; speedup vs baseline: 1.2703x; 1.2703x over previous
//
#include <hip/hip_runtime.h>
#include <math.h>

#define BATCH 8
#define NBOX 10000
#define NCLS 80
#define KSEL 8
#define MAXT 8
#define IOU_THR 0.5f
#define SCORE_THR 0.5f
#define NEGV -1000000000.0f
#define IDXINF 0x7fffffff

#define NSUB 80             // 128-row subs per class (K1): 80*128 = 10240
#define CHROWS 640          // fallback chunk = 5 subs = 640 rows; 16 chunks
typedef unsigned long long u64;

// Packed key, order-isomorphic to (val desc, idx asc); val>SCORE_THR>0 so
// float bits are monotone. bits: [51:20] value, [19:6] 16383-idx, [5:0] lane.
__device__ __forceinline__ u64 pk20(float v, int n) {
    return ((u64)__float_as_uint(v) << 20) | ((u64)(16383 - n) << 6);
}

// threshold + top-2 update (ascending n -> first-idx ties)
#define T2C(V1, I1, V2, I2, X, N)                                           \
    do {                                                                    \
        float _x = ((X) > SCORE_THR) ? (X) : NEGV;                          \
        if (_x > (V1)) { (V2)=(V1); (I2)=(I1); (V1)=_x; (I1)=(N); }         \
        else if (_x > (V2)) { (V2)=_x; (I2)=(N); }                          \
    } while (0)

// sorted-4 insertion (descending); zero keys never displace real ones
#define INS4(T1, T2, T3, T4, K)                                             \
    do { u64 _k = (K);                                                      \
        if (_k > (T1)) { (T4)=(T3); (T3)=(T2); (T2)=(T1); (T1)=_k; }        \
        else if (_k > (T2)) { (T4)=(T3); (T3)=(T2); (T2)=_k; }              \
        else if (_k > (T3)) { (T4)=(T3); (T3)=_k; }                         \
        else if (_k > (T4)) { (T4)=_k; }                                    \
    } while (0)

// IoU suppression, per-op IEEE rounding identical to numpy reference;
// union = kept_area + cand_area (validated absmax 0.0 since R1).
#define IOU_SUP(KB, KA)                                                     \
    do {                                                                    \
        float ih = fmaxf(__fsub_rn(fminf((KB).z, cb.z), fmaxf((KB).x, cb.x)), 0.0f); \
        float iw = fmaxf(__fsub_rn(fminf((KB).w, cb.w), fmaxf((KB).y, cb.y)), 0.0f); \
        float inter = __fmul_rn(ih, iw);                                    \
        float uni   = __fsub_rn(__fadd_rn((KA), carea), inter);             \
        float iou   = __fdiv_rn(inter, fmaxf(uni, 1e-9f));                  \
        if (iou > IOU_THR) sup = true;                                      \
    } while (0)

__device__ __forceinline__ float aload(const float* p) {
    return __hip_atomic_load(p, __ATOMIC_RELAXED, __HIP_MEMORY_SCOPE_AGENT);
}

// ---------------------------------------------------------------------------
// K1: per-(batch, 128-row sub) top-2 packed keys for all 80 classes (pairs).
// Reads raw (B,N,C) once, coalesced float4 across classes. (validated R10)
// ---------------------------------------------------------------------------
__global__ __launch_bounds__(320) void class_heads(
    const float* __restrict__ scores,   // (B, N, C)
    u64* __restrict__ hk,               // (B*C, NSUB, 2) packed keys
    int* __restrict__ cnt)              // (BATCH) completion counters
{
    __shared__ u64 lk[16][NCLS][2];     // 20 KB

    const int bid = blockIdx.x;         // b + 8*sub -> XCD pin
    const int b   = bid & 7;
    const int sub = bid >> 3;
    const int n0  = sub * 128;
    const int tid = threadIdx.x;
    const int q   = tid % 20;           // class quad
    const int g   = tid / 20;           // row group [0,16)

    if (bid == 0 && tid < BATCH) cnt[tid] = 0;

    const float* base = scores + ((size_t)b * NBOX + n0) * NCLS + 4 * q;

    float v10 = NEGV, v20 = NEGV, v11 = NEGV, v21 = NEGV;
    float v12 = NEGV, v22 = NEGV, v13 = NEGV, v23 = NEGV;
    int   i10 = IDXINF, i20 = IDXINF, i11 = IDXINF, i21 = IDXINF;
    int   i12 = IDXINF, i22 = IDXINF, i13 = IDXINF, i23 = IDXINF;

    #pragma unroll
    for (int k = 0; k < 8; ++k) {
        const int n = n0 + g * 8 + k;
        if (n < NBOX) {
            float4 x = *(const float4*)(base + (size_t)(g * 8 + k) * NCLS);
            T2C(v10, i10, v20, i20, x.x, n);
            T2C(v11, i11, v21, i21, x.y, n);
            T2C(v12, i12, v22, i22, x.z, n);
            T2C(v13, i13, v23, i23, x.w, n);
        }
    }

    const int c0 = 4 * q;
    lk[g][c0 + 0][0] = (v10 > SCORE_THR) ? pk20(v10, i10) : 0;
    lk[g][c0 + 0][1] = (v20 > SCORE_THR) ? pk20(v20, i20) : 0;
    lk[g][c0 + 1][0] = (v11 > SCORE_THR) ? pk20(v11, i11) : 0;
    lk[g][c0 + 1][1] = (v21 > SCORE_THR) ? pk20(v21, i21) : 0;
    lk[g][c0 + 2][0] = (v12 > SCORE_THR) ? pk20(v12, i12) : 0;
    lk[g][c0 + 2][1] = (v22 > SCORE_THR) ? pk20(v22, i22) : 0;
    lk[g][c0 + 3][0] = (v13 > SCORE_THR) ? pk20(v13, i13) : 0;
    lk[g][c0 + 3][1] = (v23 > SCORE_THR) ? pk20(v23, i23) : 0;
    __syncthreads();

    if (tid < NCLS) {
        u64 h1 = 0, h2 = 0;
        #pragma unroll
        for (int g2 = 0; g2 < 16; ++g2) {
            u64 a1 = lk[g2][tid][0], a2 = lk[g2][tid][1];   // a1 >= a2
            if (a1 > h1) { u64 t = h1; h1 = a1; h2 = (a2 > t) ? a2 : t; }
            else if (a1 > h2) h2 = a1;
        }
        u64* o = hk + ((size_t)(b * NCLS + tid) * NSUB + sub) * 2;
        o[0] = h1; o[1] = h2;
    }
}

// ---------------------------------------------------------------------------
// K2 (merged): one WAVE per class, 4 waves/block, 160 blocks.
// Stage the class's 160 hk keys in LDS; inline rank-select scatter gives the
// 8 chunks x top-8 sorted heads (no serial insert chain, no extra kernel).
// Then the validated R13 path: box gather, one-shot rank, greedy walk with
// register-buffered results, exactness check, 16x4 fallback (keys from LDS).
// Last block per batch runs the fused top-8 combine.
// ---------------------------------------------------------------------------
__global__ __launch_bounds__(256) void nms_extract(
    const u64* __restrict__ hk,
    const float* __restrict__ scores,   // raw (B,N,C)
    const float* __restrict__ boxes,    // (B,N,4)
    float* __restrict__ ws_msc,
    float* __restrict__ ws_box,         // (B*C*K, 4) floats
    int*   __restrict__ cnt,
    float* __restrict__ out)
{
    __shared__ u64    hkey[4][160];     // 5 KB  staged sub-pair keys
    __shared__ u64    kds[4][64];       // 2 KB  chunk top-8 heads (sorted)
    __shared__ float4 bds[4][64];       // 4 KB  matching boxes
    __shared__ int    lut[4][64];       // 1 KB  rank -> lane
    __shared__ float  rv[2][4];
    __shared__ int    ri[2][4];
    __shared__ int    s_old;

    const int bid = blockIdx.x;         // b + 8*grp -> XCD pin
    const int b   = bid & 7;
    const int grp = bid >> 3;
    const int w   = threadIdx.x >> 6;
    const int l   = threadIdx.x & 63;
    const int tid = threadIdx.x;
    const int c   = grp * 4 + w;
    const int bc  = b * NCLS + c;

    const float*  raw  = scores + (size_t)b * NBOX * NCLS + c;
    const float4* box4 = (const float4*)(boxes + (size_t)b * NBOX * 4);

    const int r8 = l & 7;               // rank within chunk (l>>3 = chunk)

    // ---- stage hk keys (per-wave LDS, same-wave DS ordering) ----
    {
        const u64* hp = hk + (size_t)bc * 160;
        hkey[w][l]       = hp[l];
        hkey[w][l + 64]  = hp[l + 64];
        if (l < 32) hkey[w][l + 128] = hp[l + 128];
        kds[w][l] = 0;                  // pre-zero head slots
    }

    // ---- inline rank-select: key i of chunk (i/20) scatters to its rank ---
    #pragma unroll
    for (int t = 0; t < 3; ++t) {
        const int i = l + t * 64;
        if (i < 160) {
            const u64 key = hkey[w][i];
            const int ch  = i / 20;
            const u64* kp = &hkey[w][ch * 20];
            int rank = 0;
            #pragma unroll
            for (int j = 0; j < 20; ++j)        // independent compares (ILP)
                rank += (kp[j] > key) ? 1 : 0;
            if (key != 0 && rank < 8) kds[w][ch * 8 + rank] = key;
        }
    }

    // ---- head + box (same-wave LDS read after scatter) ----
    const u64 k = kds[w][l];
    float4 bx = make_float4(0.f, 0.f, 0.f, 0.f);
    if (k) bx = box4[16383 - (int)((k >> 6) & 0x3FFF)];

    // ---- one-shot rank (uniform b128 broadcast reads) ----
    bds[w][l] = bx;
    int rank = 0;
    {
        const ulonglong2* kp = (const ulonglong2*)kds[w];
        #pragma unroll
        for (int j = 0; j < 32; ++j) {
            ulonglong2 t = kp[j];
            rank += (t.x > k) ? 1 : 0;
            rank += (t.y > k) ? 1 : 0;
        }
    }
    if (k) lut[w][rank] = l;
    const int live = __popcll(__ballot(k != 0));
    const float oa = __fmul_rn(__fsub_rn(bx.z, bx.x), __fsub_rn(bx.w, bx.y));

    // ---- greedy walk; results buffered in registers (slot l) ----
    int  kept = 0;
    u64  term = 0;
    bool sup  = false;
    u64    sk  = 0;
    float4 sbx = make_float4(0.f, 0.f, 0.f, 0.f);
    for (int r = 0; r < live; ++r) {
        const int cand = lut[w][r];                 // uniform LDS read
        const u64 smask = __ballot(sup);
        if (!((smask >> cand) & 1)) {
            const float4 kb = bds[w][cand];         // uniform LDS read
            const float kba = __fmul_rn(__fsub_rn(kb.z, kb.x),
                                        __fsub_rn(kb.w, kb.y));
            {   // own suppression update vs newly kept box
                float ih = fmaxf(__fsub_rn(fminf(kb.z, bx.z), fmaxf(kb.x, bx.x)), 0.0f);
                float iw = fmaxf(__fsub_rn(fminf(kb.w, bx.w), fmaxf(kb.y, bx.y)), 0.0f);
                float inter = __fmul_rn(ih, iw);
                float uni   = __fsub_rn(__fadd_rn(kba, oa), inter);
                float iou   = __fdiv_rn(inter, fmaxf(uni, 1e-9f));
                if (iou > IOU_THR) sup = true;
            }
            if (l == kept) { sk = kds[w][cand]; sbx = kb; }
            kept++;
            if (kept == MAXT) { term = kds[w][cand]; break; }
        }
    }

    // ---- exactness: any chunk's 8th head above the termination key? ----
    const u64 bad = __ballot((r8 == 7) && (k != 0) && (k > term));

    if (!bad) {
        if (l < kept) {
            const int o = bc * KSEL + l;
            ws_msc[o] = __uint_as_float((unsigned)(sk >> 20));
            float* ob = ws_box + (size_t)o * 4;
            ob[0] = sbx.x; ob[1] = sbx.y; ob[2] = sbx.z; ob[3] = sbx.w;
        } else if (l < MAXT) {
            const int o = bc * KSEL + l;
            ws_msc[o] = NEGV;
            float* ob = ws_box + (size_t)o * 4;
            ob[0] = 0.f; ob[1] = 0.f; ob[2] = 0.f; ob[3] = 0.f;
        }
    } else {
        // ---------- FALLBACK: validated 16x4 round loop (exact) ----------
        const int ch = l >> 2;          // 16 chunks x 5 subs (640 rows)
        const int r4 = l & 3;
        u64 k4 = 0;
        {
            u64 t1 = 0, t2 = 0, t3 = 0, t4 = 0;
            const u64* hp = &hkey[w][ch * 10];      // keys from LDS
            #pragma unroll
            for (int j = 0; j < 10; ++j) INS4(t1, t2, t3, t4, hp[j]);
            k4 = (r4 == 0) ? t1 : (r4 == 1) ? t2 : (r4 == 2) ? t3 : t4;
        }
        float4 fbx = make_float4(0.f, 0.f, 0.f, 0.f);
        float  fba = 0.f;
        if (k4) {
            const int n = 16383 - (int)((k4 >> 6) & 0x3FFF);
            fbx = box4[n];
            fba = __fmul_rn(__fsub_rn(fbx.z, fbx.x), __fsub_rn(fbx.w, fbx.y));
        }
        u64  fkey = k4 ? (k4 | (u64)l) : 0;
        bool dead = (fkey == 0);
        const u64 zb = __ballot(k4 == 0);
        bool exh  = (zb >> (l | 3)) & 1;
        u64  fl   = 0;

        float4 kb0, kb1, kb2, kb3, kb4, kb5, kb6, kb7;
        float  ka0=0, ka1=0, ka2=0, ka3=0, ka4=0, ka5=0, ka6=0, ka7=0;
        kb0 = kb1 = kb2 = kb3 = kb4 = kb5 = kb6 = kb7 = make_float4(0, 0, 0, 0);
        kept = 0;

        for (;;) {
            u64 lk_ = dead ? 0ull : fkey;
            #pragma unroll
            for (int off = 1; off < 64; off <<= 1) {
                u64 o = __shfl_xor(lk_, off, 64);
                if (o > lk_) lk_ = o;
            }
            const u64 db = __ballot(dead);
            const bool blind = (((db >> (l & ~3)) & 15ull) == 15ull)
                             && (fl != 0) && !exh;
            if (__any(blind)) {
                u64 fk = blind ? fl : 0ull;
                #pragma unroll
                for (int off = 1; off < 64; off <<= 1) {
                    u64 o = __shfl_xor(fk, off, 64);
                    if (o > fk) fk = o;
                }
                if (fk > lk_) {
                    const int chr = ((int)(fk & 63ull)) >> 2;
                    const u64 flc = fk & ~63ull;
                    const int nb  = chr * CHROWS;
                    u64 s1 = 0, s2 = 0, s3 = 0, s4 = 0;
                    #pragma unroll
                    for (int qq = 0; qq < 10; ++qq) {
                        const int n = nb + qq * 64 + l;
                        if (n < NBOX) {
                            float x = raw[(size_t)n * NCLS];
                            if (x > SCORE_THR) {
                                u64 kx = pk20(x, n);
                                if (kx < flc) INS4(s1, s2, s3, s4, kx);
                            }
                        }
                    }
                    #pragma unroll
                    for (int off = 1; off < 64; off <<= 1) {
                        u64 o1 = __shfl_xor(s1, off, 64);
                        u64 o2 = __shfl_xor(s2, off, 64);
                        u64 o3 = __shfl_xor(s3, off, 64);
                        u64 o4 = __shfl_xor(s4, off, 64);
                        INS4(s1, s2, s3, s4, o1); INS4(s1, s2, s3, s4, o2);
                        INS4(s1, s2, s3, s4, o3); INS4(s1, s2, s3, s4, o4);
                    }
                    if (ch == chr) {
                        u64 t = (r4 == 0) ? s1 : (r4 == 1) ? s2
                              : (r4 == 2) ? s3 : s4;
                        exh  = (s4 == 0);
                        fkey = t ? (t | (u64)l) : 0;
                        dead = (fkey == 0);
                        fl   = 0;
                        if (!dead) {
                            const int n = 16383 - (int)((fkey >> 6) & 0x3FFF);
                            fbx = box4[n];
                            fba = __fmul_rn(__fsub_rn(fbx.z, fbx.x),
                                            __fsub_rn(fbx.w, fbx.y));
                        }
                    }
                    continue;
                }
            }
            if (lk_ == 0ull) break;

            const int   owner = (int)(lk_ & 63ull);
            const float bv    = __uint_as_float((unsigned)(lk_ >> 20));
            float4 cb;
            cb.x = __shfl(fbx.x, owner, 64);
            cb.y = __shfl(fbx.y, owner, 64);
            cb.z = __shfl(fbx.z, owner, 64);
            cb.w = __shfl(fbx.w, owner, 64);
            const float carea = __shfl(fba, owner, 64);

            bool sup2 = false;
            {
                bool sup = false;
                if (kept > 0) IOU_SUP(kb0, ka0);
                if (kept > 1) IOU_SUP(kb1, ka1);
                if (kept > 2) IOU_SUP(kb2, ka2);
                if (kept > 3) IOU_SUP(kb3, ka3);
                if (kept > 4) IOU_SUP(kb4, ka4);
                if (kept > 5) IOU_SUP(kb5, ka5);
                if (kept > 6) IOU_SUP(kb6, ka6);
                if (kept > 7) IOU_SUP(kb7, ka7);
                sup2 = sup;
            }

            if (!sup2) {
                if (l == 0) {
                    const int o = bc * KSEL + kept;
                    ws_msc[o] = bv;
                    float* ob = ws_box + (size_t)o * 4;
                    ob[0] = cb.x; ob[1] = cb.y; ob[2] = cb.z; ob[3] = cb.w;
                }
                if      (kept == 0) { kb0 = cb; ka0 = carea; }
                else if (kept == 1) { kb1 = cb; ka1 = carea; }
                else if (kept == 2) { kb2 = cb; ka2 = carea; }
                else if (kept == 3) { kb3 = cb; ka3 = carea; }
                else if (kept == 4) { kb4 = cb; ka4 = carea; }
                else if (kept == 5) { kb5 = cb; ka5 = carea; }
                else if (kept == 6) { kb6 = cb; ka6 = carea; }
                else                { kb7 = cb; ka7 = carea; }
                kept++;
            }

            if (l == owner) dead = true;
            if (ch == (owner >> 2) && !exh) fl = lk_;
            if (kept == MAXT) break;
        }

        if (l == 0) {
            for (int k2 = kept; k2 < MAXT; ++k2) {
                const int o = bc * KSEL + k2;
                ws_msc[o] = NEGV;
                float* ob = ws_box + (size_t)o * 4;
                ob[0] = 0.f; ob[1] = 0.f; ob[2] = 0.f; ob[3] = 0.f;
            }
        }
    }

    // ---- last-block election for this batch -> fused top-8 combine ----
    __syncthreads();
    if (tid == 0) {
        __threadfence();
        s_old = atomicAdd(&cnt[b], 1);
    }
    __syncthreads();
    if (s_old != (NCLS / 4) - 1) return;
    __threadfence();

    const float* msc = ws_msc + b * NCLS * KSEL;
    float v0 = aload(msc + tid);
    float v1 = aload(msc + tid + 256);
    float v2 = (tid + 512 < NCLS * KSEL) ? aload(msc + tid + 512) : -INFINITY;

    const int OFF_SC = BATCH * MAXT * 4;
    const int OFF_CL = OFF_SC + BATCH * MAXT;
    const int OFF_VD = OFF_CL + BATCH * MAXT;

    int tot = 0;
    int p = 0;
    #pragma unroll
    for (int t = 0; t < MAXT; ++t) {
        float bv = v0; int bi = tid;
        if (v1 > bv) { bv = v1; bi = tid + 256; }   // ascending i -> first max
        if (v2 > bv) { bv = v2; bi = tid + 512; }
        #pragma unroll
        for (int off = 32; off > 0; off >>= 1) {
            float ov = __shfl_down(bv, off, 64);
            int   oi = __shfl_down(bi, off, 64);
            if (ov > bv || (ov == bv && oi < bi)) { bv = ov; bi = oi; }
        }
        if ((tid & 63) == 0) { rv[p][tid >> 6] = bv; ri[p][tid >> 6] = bi; }
        __syncthreads();
        bv = rv[p][0]; bi = ri[p][0];
        #pragma unroll
        for (int w2 = 1; w2 < 4; ++w2) {
            float ov = rv[p][w2]; int oi = ri[p][w2];
            if (ov > bv || (ov == bv && oi < bi)) { bv = ov; bi = oi; }
        }
        p ^= 1;

        const bool valid = bv > SCORE_THR;
        tot += valid ? 1 : 0;
        if (tid == t) {
            const float* sb = ws_box + ((size_t)b * NCLS * KSEL + bi) * 4;
            float bx0 = aload(sb + 0), bx1 = aload(sb + 1);
            float bx2 = aload(sb + 2), bx3 = aload(sb + 3);
            float* ob = out + ((size_t)b * MAXT + t) * 4;
            ob[0] = valid ? fminf(fmaxf(bx0, 0.0f), 1.0f) : 0.0f;
            ob[1] = valid ? fminf(fmaxf(bx1, 0.0f), 1.0f) : 0.0f;
            ob[2] = valid ? fminf(fmaxf(bx2, 0.0f), 1.0f) : 0.0f;
            ob[3] = valid ? fminf(fmaxf(bx3, 0.0f), 1.0f) : 0.0f;
            out[OFF_SC + b * MAXT + t] = valid ? bv : 0.0f;
            out[OFF_CL + b * MAXT + t] = valid ? (float)(bi >> 3) : 0.0f;
        }
        if (tid == (bi & 255)) {
            int w2 = bi >> 8;
            if (w2 == 0) v0 = -INFINITY;
            else if (w2 == 1) v1 = -INFINITY;
            else v2 = -INFINITY;
        }
    }
    if (tid == 0) out[OFF_VD + b] = (float)tot;
}

extern "C" void kernel_launch(void* const* d_in, const int* in_sizes, int n_in,
                              void* d_out, int out_size, void* d_ws, size_t ws_size,
                              hipStream_t stream) {
    const float* boxes  = (const float*)d_in[0];   // (B, N, 1, 4)
    const float* scores = (const float*)d_in[1];   // (B, N, C)
    float* out = (float*)d_out;

    // ws: hk (800 KB) | msc (20 KB) | box (80 KB) | cnt (32 B)
    const size_t nk = (size_t)BATCH * NCLS * NSUB * 2;       // 102400 keys
    char* p = (char*)d_ws;
    u64*   hk     = (u64*)p;          p += nk * 8;
    float* ws_msc = (float*)p;        p += (size_t)BATCH * NCLS * KSEL * 4;
    float* ws_box = (float*)p;        p += (size_t)BATCH * NCLS * KSEL * 16;
    int*   cnt    = (int*)p;

    class_heads<<<BATCH * NSUB, 320, 0, stream>>>(scores, hk, cnt);
    nms_extract<<<BATCH * (NCLS / 4), 256, 0, stream>>>(hk, scores, boxes,
                                                        ws_msc, ws_box,
                                                        cnt, out);
}